// Round 3
// baseline (459.650 us; speedup 1.0000x reference)
//
#include <hip/hip_runtime.h>
#include <hip/hip_fp16.h>
#include <math.h>

#define N_NODES 50000
#define N_EDGES 1600000
#define NBUCK 196          // node >> 8 buckets (50000/256)
#define EBLK 400           // edge blocks for sort
#define CHUNK 4000         // edges per block (EBLK*CHUNK == N_EDGES)
#define CSR_CAP (N_EDGES + 2048 * NBUCK + 4096)

typedef _Float16 f16x8 __attribute__((ext_vector_type(8)));
typedef _Float16 f16x4 __attribute__((ext_vector_type(4)));
typedef _Float16 f16x2 __attribute__((ext_vector_type(2)));
typedef float f32x4 __attribute__((ext_vector_type(4)));
typedef float f32x2 __attribute__((ext_vector_type(2)));

union HBits { __half h; unsigned short u; };

// ---------- dual bucket sort (dst-keyed for CSR, src-keyed for deg) ----------
__global__ __launch_bounds__(256) void k_bcount(const int* __restrict__ src,
                                                const int* __restrict__ dst,
                                                int* __restrict__ bcnt_d,
                                                int* __restrict__ bcnt_s) {
    __shared__ int lcd[256];
    __shared__ int lcs[256];
    int tid = threadIdx.x;
    lcd[tid] = 0; lcs[tid] = 0;
    __syncthreads();
    int base = blockIdx.x * CHUNK;
    for (int i = tid; i < CHUNK; i += 256) {
        atomicAdd(&lcd[dst[base + i] >> 8], 1);
        atomicAdd(&lcs[src[base + i] >> 8], 1);
    }
    __syncthreads();
    bcnt_d[blockIdx.x * 256 + tid] = lcd[tid];
    bcnt_s[blockIdx.x * 256 + tid] = lcs[tid];
}

// per-bucket scan over edge-blocks (parallel)
__global__ __launch_bounds__(256) void k_bscan1(int* __restrict__ bcnt_d,
                                                int* __restrict__ bcnt_s,
                                                int* __restrict__ btot) {
    int b = blockIdx.x & 255;
    int* bcnt = (blockIdx.x >> 8) ? bcnt_s : bcnt_d;
    int tid = threadIdx.x;
    int k0 = 2 * tid;
    int v0 = (k0 < EBLK) ? bcnt[k0 * 256 + b] : 0;
    int v1 = (k0 + 1 < EBLK) ? bcnt[(k0 + 1) * 256 + b] : 0;
    int pair = v0 + v1;
    __shared__ int s[256];
    s[tid] = pair;
    __syncthreads();
    for (int off = 1; off < 256; off <<= 1) {
        int t = (tid >= off) ? s[tid - off] : 0;
        __syncthreads();
        s[tid] += t;
        __syncthreads();
    }
    int excl = s[tid] - pair;
    if (k0 < EBLK)     bcnt[k0 * 256 + b] = excl;
    if (k0 + 1 < EBLK) bcnt[(k0 + 1) * 256 + b] = excl + v0;
    if (tid == 255) btot[(blockIdx.x >> 8) * 256 + b] = s[255];
}

__global__ __launch_bounds__(256) void k_bscan2(const int* __restrict__ btot,
                                                int* __restrict__ bstart_d,
                                                int* __restrict__ bstart_s) {
    __shared__ int s[256];
    int b = threadIdx.x;
    int v = btot[b];
    s[b] = v;
    __syncthreads();
    for (int off = 1; off < 256; off <<= 1) {
        int t = (b >= off) ? s[b - off] : 0;
        __syncthreads();
        s[b] += t;
        __syncthreads();
    }
    bstart_d[b] = s[b] - v;
    if (b == 0) bstart_d[256] = N_EDGES;
    __syncthreads();
    int v2 = btot[256 + b];
    s[b] = v2;
    __syncthreads();
    for (int off = 1; off < 256; off <<= 1) {
        int t = (b >= off) ? s[b - off] : 0;
        __syncthreads();
        s[b] += t;
        __syncthreads();
    }
    bstart_s[b] = s[b] - v2;
    if (b == 0) bstart_s[256] = N_EDGES;
}

// R15: LDS-staged scatter. Old version's random 8B/4B global writes dirtied
// a 64B line each (WRITE_SIZE 56 MB for 19.2 MB logical). New: locally sort
// the chunk in LDS, then copy out bucket-runs so consecutive lanes hit
// consecutive addresses. Bucket id rides in unused record bits (consumers
// mask). dsw: {src | dst_local<<16 | bucket<<24, f32 w}; ssw: full src (16b)
// | f16w<<16.
__global__ __launch_bounds__(256) void k_bscatter(const int* __restrict__ src,
                                                  const int* __restrict__ dst,
                                                  const float* __restrict__ w,
                                                  const int* __restrict__ bcnt_d,
                                                  const int* __restrict__ bcnt_s,
                                                  const int* __restrict__ bstart_d,
                                                  const int* __restrict__ bstart_s,
                                                  uint2* __restrict__ dsw,
                                                  unsigned* __restrict__ ssw) {
    __shared__ uint2 sbufd[CHUNK];       // 32 KB bucket-sorted dsw records
    __shared__ unsigned sbufs[CHUNK];    // 16 KB bucket-sorted ssw records
    __shared__ int lcd[256];
    __shared__ int lcs[256];
    __shared__ int curd_l[256];
    __shared__ int curs_l[256];
    __shared__ int gbase_d[256];
    __shared__ int gbase_s[256];
    int tid = threadIdx.x;
    lcd[tid] = 0; lcs[tid] = 0;
    __syncthreads();
    int base = blockIdx.x * CHUNK;
    // pass A: local counts
    for (int i = tid; i < CHUNK; i += 256) {
        atomicAdd(&lcd[dst[base + i] >> 8], 1);
        atomicAdd(&lcs[src[base + i] >> 8], 1);
    }
    __syncthreads();
    // in-place inclusive scans -> local exclusive offsets
    int vd = lcd[tid], vs = lcs[tid];
    for (int off = 1; off < 256; off <<= 1) {
        int td = (tid >= off) ? lcd[tid - off] : 0;
        int ts = (tid >= off) ? lcs[tid - off] : 0;
        __syncthreads();
        lcd[tid] += td; lcs[tid] += ts;
        __syncthreads();
    }
    int exd = lcd[tid] - vd, exs = lcs[tid] - vs;
    curd_l[tid] = exd;
    curs_l[tid] = exs;
    gbase_d[tid] = bcnt_d[blockIdx.x * 256 + tid] + bstart_d[tid] - exd;
    gbase_s[tid] = bcnt_s[blockIdx.x * 256 + tid] + bstart_s[tid] - exs;
    __syncthreads();
    // pass B: place into LDS at locally-sorted positions (chunk re-read is L1-hot)
    for (int i = tid; i < CHUNK; i += 256) {
        int d = dst[base + i];
        int ss = src[base + i];
        float wi = w[base + i];
        int p = atomicAdd(&curd_l[d >> 8], 1);   // LDS atomic
        uint2 r;
        r.x = (unsigned)ss | ((unsigned)(d & 255) << 16) | ((unsigned)(d >> 8) << 24);
        r.y = __float_as_uint(wi);
        sbufd[p] = r;
        int q = atomicAdd(&curs_l[ss >> 8], 1);  // LDS atomic
        HBits hw; hw.h = __float2half(wi);
        sbufs[q] = (unsigned)ss | ((unsigned)hw.u << 16);
    }
    __syncthreads();
    // pass C: coalesced copy-out (consecutive i -> consecutive addr per run)
    for (int i = tid; i < CHUNK; i += 256) {
        uint2 r = sbufd[i];
        dsw[gbase_d[(r.x >> 24) & 255] + i] = r;
    }
    for (int i = tid; i < CHUNK; i += 256) {
        unsigned rs = sbufs[i];
        ssw[gbase_s[(rs >> 8) & 255] + i] = rs;
    }
}

// deg per src-bucket -> dinv (f16 w partials: ~0.05% deg error, negligible)
__global__ __launch_bounds__(256) void k_sdeg(const unsigned* __restrict__ ssw,
                                              const int* __restrict__ bstart_s,
                                              float* __restrict__ dinv) {
    __shared__ float h[256];
    int tid = threadIdx.x;
    int b = blockIdx.x;
    h[tid] = 0.f;
    __syncthreads();
    int e0 = bstart_s[b], e1 = bstart_s[b + 1];
    for (int i = e0 + tid; i < e1; i += 256) {
        unsigned r = ssw[i];
        HBits hb; hb.u = (unsigned short)(r >> 16);
        atomicAdd(&h[r & 255], __half2float(hb.h));  // LDS atomic
    }
    __syncthreads();
    int node = (b << 8) + tid;
    if (node < N_NODES) {
        float d = h[tid];
        dinv[node] = d > 0.f ? rsqrtf(fmaxf(d, 1e-30f)) : 0.f;
    }
}

// per-bucket CSR build + inline norm. Rows PADDED to multiples of 8 with
// zero entries (src=0, norm=0) so every row start is 8-aligned and spmm needs
// no guarded tail. csr entry = src(16b) | f16norm<<16. ri[node]={start,pcnt}.
__global__ __launch_bounds__(256) void k_bcsr(const uint2* __restrict__ dsw,
                                              const int* __restrict__ bstart_d,
                                              const float* __restrict__ dinv,
                                              uint2* __restrict__ ri,
                                              unsigned* __restrict__ csr4) {
    __shared__ int ncnt[256];
    __shared__ int cur[256];
    __shared__ int sc[256];
    __shared__ float ldinv[256];
    int tid = threadIdx.x;
    int b = blockIdx.x;
    int node = (b << 8) + tid;
    ncnt[tid] = 0;
    ldinv[tid] = (node < N_NODES) ? dinv[node] : 0.f;
    __syncthreads();
    int e0 = bstart_d[b], e1 = bstart_d[b + 1];
    for (int i = e0 + tid; i < e1; i += 256)
        atomicAdd(&ncnt[(dsw[i].x >> 16) & 255], 1);  // LDS atomic
    __syncthreads();
    int v = ncnt[tid];
    int pc = (v + 7) & ~7;                            // padded count
    sc[tid] = pc;
    __syncthreads();
    for (int off = 1; off < 256; off <<= 1) {
        int t = (tid >= off) ? sc[tid - off] : 0;
        __syncthreads();
        sc[tid] += t;
        __syncthreads();
    }
    int excl = sc[tid] - pc;
    cur[tid] = excl;
    int pbase = ((e0 + 7) & ~7) + 2048 * b;
    if (node < N_NODES) {
        uint2 r; r.x = (unsigned)(pbase + excl); r.y = (unsigned)pc;
        ri[node] = r;
    }
    __syncthreads();
    for (int i = e0 + tid; i < e1; i += 256) {
        uint2 sw = dsw[i];
        int srcn = sw.x & 0xFFFF;
        int ld = (sw.x >> 16) & 255;
        int p = pbase + atomicAdd(&cur[ld], 1);  // LDS atomic
        float nv = -dinv[srcn] * __uint_as_float(sw.y) * ldinv[ld];
        HBits hb; hb.h = __float2half(nv);
        csr4[p] = (unsigned)srcn | ((unsigned)hb.u << 16);
    }
    __syncthreads();
    // zero-norm fillers
    int st = pbase + excl;
    for (int i = v; i < pc; i++) csr4[st + i] = 0u;
}

// merged prep: x fp32 -> X f16 (blocks 0..6249), Wt builds (rest).
// Wt[n*128 + k], n in [0,3C): slice0 = 2*W2, slice1 = W1, slice2 = W0 - W2.
__device__ inline void wt_one(const float* __restrict__ W, __half* __restrict__ Wt,
                              int C, int i) {
    int n = i >> 7, k = i & 127;
    int slice = n / C, c = n % C;
    float v;
    if (slice == 0)      v = 2.f * W[(size_t)(256 + k) * C + c];
    else if (slice == 1) v = W[(size_t)(128 + k) * C + c];
    else                 v = W[(size_t)k * C + c] - W[(size_t)(256 + k) * C + c];
    Wt[i] = __float2half(v);
}

__global__ __launch_bounds__(256) void k_prep(const float* __restrict__ x,
                                              __half* __restrict__ X,
                                              const float* __restrict__ W0,
                                              const float* __restrict__ W1,
                                              const float* __restrict__ W2,
                                              __half* __restrict__ Wt0,
                                              __half* __restrict__ Wt1,
                                              __half* __restrict__ Wt2) {
    int bid = blockIdx.x, tid = threadIdx.x;
    if (bid < 6250) {
        int i = bid * 256 + tid;          // float4 index, 1.6M total
        float4 v = *(const float4*)&x[(size_t)i * 4];
        f16x4 o;
        o[0] = (_Float16)v.x; o[1] = (_Float16)v.y;
        o[2] = (_Float16)v.z; o[3] = (_Float16)v.w;
        *(f16x4*)&X[(size_t)i * 4] = o;
    } else if (bid < 6250 + 192) {
        wt_one(W0, Wt0, 128, (bid - 6250) * 256 + tid);
    } else if (bid < 6250 + 384) {
        wt_one(W1, Wt1, 128, (bid - 6250 - 192) * 256 + tid);
    } else {
        wt_one(W2, Wt2, 64, (bid - 6250 - 384) * 256 + tid);
    }
}

// ---------- SpMM: one wave per node, wide aligned csr loads ------
// R13/R14: fp8 gathers (P8/TMP8). R15: fp8 FW=128 path uses 8 lanes x
// dwordx4 per row (16 features/lane) instead of 16 x dwordx2 -> halves
// VMEM instruction count (probe of the request-bound theory; segments
// per edge unchanged at 2x64B).
__device__ inline void mac_pair(const __half* __restrict__ Tbase, unsigned ea,
                                unsigned eb, int stin, float acc[8]) {
    f16x8 r0 = *(const f16x8*)&Tbase[(size_t)(ea & 0xFFFFu) * stin];
    f16x8 r1 = *(const f16x8*)&Tbase[(size_t)(eb & 0xFFFFu) * stin];
    unsigned np = (ea >> 16) | (eb & 0xFFFF0000u);
    f16x2 nv; __builtin_memcpy(&nv, &np, 4);
    #pragma unroll
    for (int f = 0; f < 8; f++) {
        f16x2 h; h[0] = r0[f]; h[1] = r1[f];
        acc[f] = __builtin_amdgcn_fdot2(h, nv, acc[f], false);
    }
}

// convert 8 fp8 (uint2) + f16 norm (hi bits of ce) -> acc += n * v
__device__ inline void macv_f8(uint2 v, unsigned ce, float acc[8]) {
    HBits hb; hb.u = (unsigned short)(ce >> 16);
    float n = __half2float(hb.h);
    f32x2 p0 = __builtin_amdgcn_cvt_pk_f32_fp8(v.x, false);
    f32x2 p1 = __builtin_amdgcn_cvt_pk_f32_fp8(v.x, true);
    f32x2 p2 = __builtin_amdgcn_cvt_pk_f32_fp8(v.y, false);
    f32x2 p3 = __builtin_amdgcn_cvt_pk_f32_fp8(v.y, true);
    acc[0] = fmaf(n, p0[0], acc[0]);
    acc[1] = fmaf(n, p0[1], acc[1]);
    acc[2] = fmaf(n, p1[0], acc[2]);
    acc[3] = fmaf(n, p1[1], acc[3]);
    acc[4] = fmaf(n, p2[0], acc[4]);
    acc[5] = fmaf(n, p2[1], acc[5]);
    acc[6] = fmaf(n, p3[0], acc[6]);
    acc[7] = fmaf(n, p3[1], acc[7]);
}

__device__ inline void mac_e8(const unsigned char* __restrict__ Tb, unsigned ce,
                              int stin, float acc[8]) {
    uint2 v = *(const uint2*)&Tb[(size_t)(ce & 0xFFFFu) * (size_t)stin];
    macv_f8(v, ce, acc);
}

// 16 fp8 (uint4) + f16 norm -> acc[16] += n * v
__device__ inline void macv_f8q(uint4 v, unsigned ce, float acc[16]) {
    HBits hb; hb.u = (unsigned short)(ce >> 16);
    float n = __half2float(hb.h);
    f32x2 p;
    p = __builtin_amdgcn_cvt_pk_f32_fp8(v.x, false);
    acc[0] = fmaf(n, p[0], acc[0]);  acc[1] = fmaf(n, p[1], acc[1]);
    p = __builtin_amdgcn_cvt_pk_f32_fp8(v.x, true);
    acc[2] = fmaf(n, p[0], acc[2]);  acc[3] = fmaf(n, p[1], acc[3]);
    p = __builtin_amdgcn_cvt_pk_f32_fp8(v.y, false);
    acc[4] = fmaf(n, p[0], acc[4]);  acc[5] = fmaf(n, p[1], acc[5]);
    p = __builtin_amdgcn_cvt_pk_f32_fp8(v.y, true);
    acc[6] = fmaf(n, p[0], acc[6]);  acc[7] = fmaf(n, p[1], acc[7]);
    p = __builtin_amdgcn_cvt_pk_f32_fp8(v.z, false);
    acc[8] = fmaf(n, p[0], acc[8]);  acc[9] = fmaf(n, p[1], acc[9]);
    p = __builtin_amdgcn_cvt_pk_f32_fp8(v.z, true);
    acc[10] = fmaf(n, p[0], acc[10]); acc[11] = fmaf(n, p[1], acc[11]);
    p = __builtin_amdgcn_cvt_pk_f32_fp8(v.w, false);
    acc[12] = fmaf(n, p[0], acc[12]); acc[13] = fmaf(n, p[1], acc[13]);
    p = __builtin_amdgcn_cvt_pk_f32_fp8(v.w, true);
    acc[14] = fmaf(n, p[0], acc[14]); acc[15] = fmaf(n, p[1], acc[15]);
}

template <int ST_IN, int ST_ADD, int ST_OUT, int FW, int SIG, int F32, int GF8,
          int F8OUT>
__global__ __launch_bounds__(256) void k_spmm(const void* __restrict__ Xin,
                                              const __half* __restrict__ Add,
                                              void* __restrict__ outp,
                                              const float* __restrict__ bias,
                                              const uint2* __restrict__ ri,
                                              const unsigned* __restrict__ csr4) {
    constexpr int FPL = (GF8 && FW == 128) ? 16 : 8;  // features per lane
    constexpr int NL = FW / FPL;    // lanes per edge
    constexpr int EG = 64 / NL;     // edge groups
    int node = blockIdx.x * 4 + (threadIdx.x >> 6);
    int lane = threadIdx.x & 63;
    int eg = lane / NL;
    int fs = lane % NL;
    uint2 rv = ri[node];
    int s = (int)rv.x;
    int e = s + (int)rv.y;                  // count is multiple of 8
    const __half* Tbase = (const __half*)Xin + fs * 8;
    const unsigned char* Tb8 = (const unsigned char*)Xin + fs * FPL;
    float acc[FPL];
    #pragma unroll
    for (int f = 0; f < FPL; f++) acc[f] = 0.f;

    int j = s;
    if (GF8 && FW == 128) {                 // fp8, 8 lanes x 16B per row
        for (; j + 32 <= e; j += 32) {      // 8 groups x 4 edges
            uint4 c0 = *(const uint4*)&csr4[j + 4 * eg];
            unsigned ce[4] = {c0.x, c0.y, c0.z, c0.w};
            uint4 g[4];
            #pragma unroll
            for (int k = 0; k < 4; k++)
                g[k] = *(const uint4*)&Tb8[(size_t)(ce[k] & 0xFFFFu) * (size_t)ST_IN];
            #pragma unroll
            for (int k = 0; k < 4; k++) macv_f8q(g[k], ce[k], acc);
        }
        if (j + 16 <= e) {                  // 8 groups x 2 edges
            uint2 c = *(const uint2*)&csr4[j + 2 * eg];
            uint4 g0 = *(const uint4*)&Tb8[(size_t)(c.x & 0xFFFFu) * (size_t)ST_IN];
            uint4 g1 = *(const uint4*)&Tb8[(size_t)(c.y & 0xFFFFu) * (size_t)ST_IN];
            macv_f8q(g0, c.x, acc);
            macv_f8q(g1, c.y, acc);
            j += 16;
        }
        if (j + 8 <= e) {                   // 8 groups x 1 edge
            unsigned c = csr4[j + eg];
            uint4 g0 = *(const uint4*)&Tb8[(size_t)(c & 0xFFFFu) * (size_t)ST_IN];
            macv_f8q(g0, c, acc);
        }
    } else if (GF8) {                       // fp8, FW=64, EG=8: 4 edges/iter
        for (; j + 32 <= e; j += 32) {
            uint4 c0 = *(const uint4*)&csr4[j + 4 * eg];
            unsigned ce[4] = {c0.x, c0.y, c0.z, c0.w};
            uint2 g[4];
            #pragma unroll
            for (int k = 0; k < 4; k++)
                g[k] = *(const uint2*)&Tb8[(size_t)(ce[k] & 0xFFFFu) * (size_t)ST_IN];
            #pragma unroll
            for (int k = 0; k < 4; k++) macv_f8(g[k], ce[k], acc);
        }
        if (j + 16 <= e) {
            uint2 c = *(const uint2*)&csr4[j + 2 * eg];
            mac_e8(Tb8, c.x, ST_IN, acc);
            mac_e8(Tb8, c.y, ST_IN, acc);
            j += 16;
        }
        if (j + 8 <= e) {
            uint2 c = *(const uint2*)&csr4[j + 2 * (eg & 3)];
            unsigned ea = c.x, eb = c.y;
            if (eg >= 4) { ea &= 0xFFFFu; eb &= 0xFFFFu; }  // zero norms
            mac_e8(Tb8, ea, ST_IN, acc);
            mac_e8(Tb8, eb, ST_IN, acc);
        }
    } else if (EG == 4) {                   // f16, FW=128 (unused now)
        for (; j + 32 <= e; j += 32) {
            uint4 c0 = *(const uint4*)&csr4[j + 4 * eg];
            uint4 c1 = *(const uint4*)&csr4[j + 16 + 4 * eg];
            unsigned ea[4] = {c0.x, c0.z, c1.x, c1.z};
            unsigned eb[4] = {c0.y, c0.w, c1.y, c1.w};
            f16x8 r0[4], r1[4];
            #pragma unroll
            for (int k = 0; k < 4; k++) {
                r0[k] = *(const f16x8*)&Tbase[(size_t)(ea[k] & 0xFFFFu) * ST_IN];
                r1[k] = *(const f16x8*)&Tbase[(size_t)(eb[k] & 0xFFFFu) * ST_IN];
            }
            #pragma unroll
            for (int k = 0; k < 4; k++) {
                unsigned np = (ea[k] >> 16) | (eb[k] & 0xFFFF0000u);
                f16x2 nv; __builtin_memcpy(&nv, &np, 4);
                #pragma unroll
                for (int f = 0; f < 8; f++) {
                    f16x2 h; h[0] = r0[k][f]; h[1] = r1[k][f];
                    acc[f] = __builtin_amdgcn_fdot2(h, nv, acc[f], false);
                }
            }
        }
        if (j + 16 <= e) {
            uint4 c0 = *(const uint4*)&csr4[j + 4 * eg];
            mac_pair(Tbase, c0.x, c0.y, ST_IN, acc);
            mac_pair(Tbase, c0.z, c0.w, ST_IN, acc);
            j += 16;
        }
        if (j + 8 <= e) {
            uint2 c = *(const uint2*)&csr4[j + 2 * eg];
            mac_pair(Tbase, c.x, c.y, ST_IN, acc);
        }
    } else {                                // f16, FW=64, EG=8
        for (; j + 32 <= e; j += 32) {
            uint4 c0 = *(const uint4*)&csr4[j + 4 * eg];
            unsigned ea[2] = {c0.x, c0.z};
            unsigned eb[2] = {c0.y, c0.w};
            f16x8 r0[2], r1[2];
            #pragma unroll
            for (int k = 0; k < 2; k++) {
                r0[k] = *(const f16x8*)&Tbase[(size_t)(ea[k] & 0xFFFFu) * ST_IN];
                r1[k] = *(const f16x8*)&Tbase[(size_t)(eb[k] & 0xFFFFu) * ST_IN];
            }
            #pragma unroll
            for (int k = 0; k < 2; k++) {
                unsigned np = (ea[k] >> 16) | (eb[k] & 0xFFFF0000u);
                f16x2 nv; __builtin_memcpy(&nv, &np, 4);
                #pragma unroll
                for (int f = 0; f < 8; f++) {
                    f16x2 h; h[0] = r0[k][f]; h[1] = r1[k][f];
                    acc[f] = __builtin_amdgcn_fdot2(h, nv, acc[f], false);
                }
            }
        }
        if (j + 16 <= e) {
            uint2 c = *(const uint2*)&csr4[j + 2 * eg];
            mac_pair(Tbase, c.x, c.y, ST_IN, acc);
            j += 16;
        }
        if (j + 8 <= e) {
            uint2 c = *(const uint2*)&csr4[j + 2 * (eg & 3)];
            unsigned ea = c.x, eb = c.y;
            if (eg >= 4) { ea &= 0xFFFFu; eb &= 0xFFFFu; }  // zero norms (dup groups)
            mac_pair(Tbase, ea, eb, ST_IN, acc);
        }
    }
    // reduce edge-group partials
    #pragma unroll
    for (int f = 0; f < FPL; f++)
        for (int m = NL; m < 64; m <<= 1)
            acc[f] += __shfl_xor(acc[f], m);
    if (eg == 0) {
        float v[FPL];
        #pragma unroll
        for (int c = 0; c < FPL / 8; c++) {
            f16x8 av = *(const f16x8*)&Add[(size_t)node * ST_ADD + fs * FPL + c * 8];
            #pragma unroll
            for (int f = 0; f < 8; f++) v[c * 8 + f] = acc[c * 8 + f] + (float)av[f];
        }
        if (SIG) {
            #pragma unroll
            for (int f = 0; f < FPL; f++) {
                v[f] += bias[fs * FPL + f];
                v[f] = 1.f / (1.f + expf(-v[f]));
            }
        }
        if (F32) {                           // only instantiated with FPL=8
            float* o = (float*)outp + (size_t)node * ST_OUT + fs * 8;
            float4 o0; o0.x = v[0]; o0.y = v[1]; o0.z = v[2]; o0.w = v[3];
            float4 o1; o1.x = v[4]; o1.y = v[5]; o1.z = v[6]; o1.w = v[7];
            *(float4*)&o[0] = o0;
            *(float4*)&o[4] = o1;
        } else if (F8OUT) {
            #pragma unroll
            for (int c = 0; c < FPL / 8; c++) {
                int w0 = __builtin_amdgcn_cvt_pk_fp8_f32(v[c*8+0], v[c*8+1], 0, false);
                w0 = __builtin_amdgcn_cvt_pk_fp8_f32(v[c*8+2], v[c*8+3], w0, true);
                int w1 = __builtin_amdgcn_cvt_pk_fp8_f32(v[c*8+4], v[c*8+5], 0, false);
                w1 = __builtin_amdgcn_cvt_pk_fp8_f32(v[c*8+6], v[c*8+7], w1, true);
                uint2 o; o.x = (unsigned)w0; o.y = (unsigned)w1;
                *(uint2*)((unsigned char*)outp + (size_t)node * ST_OUT + fs * FPL + c * 8) = o;
            }
        } else {
            #pragma unroll
            for (int c = 0; c < FPL / 8; c++) {
                f16x8 o;
                #pragma unroll
                for (int f = 0; f < 8; f++) o[f] = (_Float16)v[c * 8 + f];
                *(f16x8*)((__half*)outp + (size_t)node * ST_OUT + fs * FPL + c * 8) = o;
            }
        }
    }
}

// ---------- MFMA GEMM: [P8|G] = X[M x 128] @ Wt^T ---------------------------
// P slice (first CC cols, = 2*W2 weights) written as fp8 e4m3 to packed P8
// [M x CC]; Q,S slices written f16 to G stride STG=2*CC (Q@0, S@CC).
template <int CC, int STG>
__global__ __launch_bounds__(256) void k_gemm(const __half* __restrict__ A,
                                              const __half* __restrict__ Wt,
                                              __half* __restrict__ G,
                                              unsigned char* __restrict__ P8,
                                              int M) {
    constexpr int N3 = 3 * CC;
    constexpr int NF = N3 / 16;
    constexpr int NP = CC / 16;       // fp8 P fragments
    __shared__ _Float16 As[64][40];
    __shared__ _Float16 Bs[N3][40];
    int tid = threadIdx.x;
    int wave = tid >> 6, lane = tid & 63;
    int lm = lane & 15, lq = lane >> 4;
    int m0 = blockIdx.x * 64;
    f32x4 acc[NF];
    for (int nf = 0; nf < NF; nf++) acc[nf] = (f32x4)0.0f;

    for (int k0 = 0; k0 < 128; k0 += 32) {
        {
            int r = tid >> 2, q = tid & 3;
            int row = m0 + r;
            if (row >= M) row = M - 1;
            *(f16x8*)&As[r][q * 8] = *(const f16x8*)&A[(size_t)row * 128 + k0 + q * 8];
        }
        for (int i = 0; i < N3 / 64; i++) {
            int idx = tid + i * 256;
            int n = idx >> 2, q = idx & 3;
            *(f16x8*)&Bs[n][q * 8] = *(const f16x8*)&Wt[(size_t)n * 128 + k0 + q * 8];
        }
        __syncthreads();
        f16x8 a = *(const f16x8*)&As[wave * 16 + lm][lq * 8];
        for (int nf = 0; nf < NF; nf++) {
            f16x8 b = *(const f16x8*)&Bs[nf * 16 + lm][lq * 8];
            acc[nf] = __builtin_amdgcn_mfma_f32_16x16x32_f16(a, b, acc[nf], 0, 0, 0);
        }
        __syncthreads();
    }
    for (int nf = 0; nf < NF; nf++) {
        for (int r = 0; r < 4; r++) {
            int grow = m0 + wave * 16 + lq * 4 + r;
            int col = nf * 16 + lm;
            if (grow < M) {
                if (nf < NP) {
                    int pk = __builtin_amdgcn_cvt_pk_fp8_f32(acc[nf][r], acc[nf][r],
                                                             0, false);
                    P8[(size_t)grow * CC + col] = (unsigned char)(pk & 0xFF);
                } else {
                    G[(size_t)grow * STG + (col - CC)] = __float2half(acc[nf][r]);
                }
            }
        }
    }
}

extern "C" void kernel_launch(void* const* d_in, const int* in_sizes, int n_in,
                              void* d_out, int out_size, void* d_ws, size_t ws_size,
                              hipStream_t stream) {
    const float* x  = (const float*)d_in[0];
    const int*   ei = (const int*)d_in[1];
    const float* ew = (const float*)d_in[2];
    const float* W0 = (const float*)d_in[3];
    const float* b0 = (const float*)d_in[4];
    const float* W1 = (const float*)d_in[5];
    const float* b1 = (const float*)d_in[6];
    const float* W2 = (const float*)d_in[7];
    const float* b2 = (const float*)d_in[8];
    const int* src = ei;
    const int* dst = ei + N_EDGES;

    char* ws = (char*)d_ws;
    size_t off = 0;
    auto alloc = [&](size_t bytes) -> char* {
        size_t p = (off + 255) & ~(size_t)255;
        off = p + bytes;
        return ws + p;
    };
    __half*   X      = (__half*)alloc((size_t)N_NODES * 128 * 2);
    __half*   G      = (__half*)alloc((size_t)N_NODES * 256 * 2);   // [Q|S], stride 256
    __half*   TMP    = (__half*)alloc((size_t)N_NODES * 128 * 2);   // L*P + Q (layer 2, f16)
    unsigned char* P8 = (unsigned char*)alloc((size_t)N_NODES * 128); // fp8 P, packed
    unsigned char* TMP8 = (unsigned char*)alloc((size_t)N_NODES * 128); // fp8 TMP (L0/L1)
    unsigned* csr4   = (unsigned*)alloc((size_t)CSR_CAP * 4);       // padded CSR
    uint2*    ri     = (uint2*)alloc((size_t)N_NODES * 8);          // (start, pcount)
    uint2*    dsw    = (uint2*)alloc((size_t)N_EDGES * 8);
    unsigned* ssw    = (unsigned*)alloc((size_t)N_EDGES * 4);       // src | f16w<<16
    int*      bcnt_d = (int*)alloc((size_t)EBLK * 256 * 4);
    int*      bcnt_s = (int*)alloc((size_t)EBLK * 256 * 4);
    int*      btot   = (int*)alloc(512 * 4);
    int*      bstart_d = (int*)alloc(257 * 4);
    int*      bstart_s = (int*)alloc(257 * 4);
    float*    dinv   = (float*)alloc((size_t)N_NODES * 4);
    __half*   Wt0    = (__half*)alloc((size_t)384 * 128 * 2);
    __half*   Wt1    = (__half*)alloc((size_t)384 * 128 * 2);
    __half*   Wt2    = (__half*)alloc((size_t)192 * 128 * 2);

    // dual bucket sort; zero device-scope atomics anywhere
    k_bcount<<<EBLK, 256, 0, stream>>>(src, dst, bcnt_d, bcnt_s);
    k_bscan1<<<512, 256, 0, stream>>>(bcnt_d, bcnt_s, btot);
    k_bscan2<<<1, 256, 0, stream>>>(btot, bstart_d, bstart_s);
    k_bscatter<<<EBLK, 256, 0, stream>>>(src, dst, ew, bcnt_d, bcnt_s,
                                         bstart_d, bstart_s, dsw, ssw);
    k_sdeg<<<NBUCK, 256, 0, stream>>>(ssw, bstart_s, dinv);
    k_bcsr<<<NBUCK, 256, 0, stream>>>(dsw, bstart_d, dinv, ri, csr4);

    k_prep<<<6250 + 192 + 192 + 96, 256, 0, stream>>>(x, X, W0, W1, W2, Wt0, Wt1, Wt2);

    int gb = (N_NODES + 63) / 64;   // 782
    int sb = N_NODES / 4;           // 12500
    // layer 0: P8 = fp8(X @ 2W2), G = f16(X @ [W1 | W0-W2])  (Q@0, S@128)
    // TMP8 = fp8(L*P + Q);  X = sigmoid(L*TMP8 + S + b0)
    k_gemm<128, 256><<<gb, 256, 0, stream>>>(X, Wt0, G, P8, N_NODES);
    k_spmm<128, 256, 128, 128, 0, 0, 1, 1><<<sb, 256, 0, stream>>>(P8, G, TMP8,
                                                                   nullptr, ri, csr4);
    k_spmm<128, 256, 128, 128, 1, 0, 1, 0><<<sb, 256, 0, stream>>>(TMP8, G + 128, X,
                                                                   b0, ri, csr4);
    // layer 1
    k_gemm<128, 256><<<gb, 256, 0, stream>>>(X, Wt1, G, P8, N_NODES);
    k_spmm<128, 256, 128, 128, 0, 0, 1, 1><<<sb, 256, 0, stream>>>(P8, G, TMP8,
                                                                   nullptr, ri, csr4);
    k_spmm<128, 256, 128, 128, 1, 0, 1, 0><<<sb, 256, 0, stream>>>(TMP8, G + 128, X,
                                                                   b1, ri, csr4);
    // layer 2 (C=64): G stride 128 (Q@0, S@64); TMP stays f16 (feeds output)
    k_gemm<64, 128><<<gb, 256, 0, stream>>>(X, Wt2, G, P8, N_NODES);
    k_spmm<64, 128, 64, 64, 0, 0, 1, 0><<<sb, 256, 0, stream>>>(P8, G, TMP,
                                                                nullptr, ri, csr4);
    k_spmm<64, 128, 64, 64, 1, 1, 0, 0><<<sb, 256, 0, stream>>>(TMP, G + 64, d_out,
                                                                b2, ri, csr4);
}

// Round 4
// 399.337 us; speedup vs baseline: 1.1510x; 1.1510x over previous
//
#include <hip/hip_runtime.h>
#include <hip/hip_fp16.h>
#include <math.h>

#define N_NODES 50000
#define N_EDGES 1600000
#define NBUCK 196          // node >> 8 buckets (50000/256)
#define EBLK 400           // edge blocks for sort
#define CHUNK 4000         // edges per block (EBLK*CHUNK == N_EDGES)
#define CSR_CAP (N_EDGES + 2048 * NBUCK + 4096)

typedef _Float16 f16x8 __attribute__((ext_vector_type(8)));
typedef _Float16 f16x4 __attribute__((ext_vector_type(4)));
typedef _Float16 f16x2 __attribute__((ext_vector_type(2)));
typedef float f32x4 __attribute__((ext_vector_type(4)));
typedef float f32x2 __attribute__((ext_vector_type(2)));

union HBits { __half h; unsigned short u; };

// ---------- dual bucket sort (dst-keyed for CSR, src-keyed for deg) ----------
__global__ __launch_bounds__(256) void k_bcount(const int* __restrict__ src,
                                                const int* __restrict__ dst,
                                                int* __restrict__ bcnt_d,
                                                int* __restrict__ bcnt_s) {
    __shared__ int lcd[256];
    __shared__ int lcs[256];
    int tid = threadIdx.x;
    lcd[tid] = 0; lcs[tid] = 0;
    __syncthreads();
    int base = blockIdx.x * CHUNK;
    for (int i = tid; i < CHUNK; i += 256) {
        atomicAdd(&lcd[dst[base + i] >> 8], 1);
        atomicAdd(&lcs[src[base + i] >> 8], 1);
    }
    __syncthreads();
    bcnt_d[blockIdx.x * 256 + tid] = lcd[tid];
    bcnt_s[blockIdx.x * 256 + tid] = lcs[tid];
}

// per-bucket scan over edge-blocks (parallel)
__global__ __launch_bounds__(256) void k_bscan1(int* __restrict__ bcnt_d,
                                                int* __restrict__ bcnt_s,
                                                int* __restrict__ btot) {
    int b = blockIdx.x & 255;
    int* bcnt = (blockIdx.x >> 8) ? bcnt_s : bcnt_d;
    int tid = threadIdx.x;
    int k0 = 2 * tid;
    int v0 = (k0 < EBLK) ? bcnt[k0 * 256 + b] : 0;
    int v1 = (k0 + 1 < EBLK) ? bcnt[(k0 + 1) * 256 + b] : 0;
    int pair = v0 + v1;
    __shared__ int s[256];
    s[tid] = pair;
    __syncthreads();
    for (int off = 1; off < 256; off <<= 1) {
        int t = (tid >= off) ? s[tid - off] : 0;
        __syncthreads();
        s[tid] += t;
        __syncthreads();
    }
    int excl = s[tid] - pair;
    if (k0 < EBLK)     bcnt[k0 * 256 + b] = excl;
    if (k0 + 1 < EBLK) bcnt[(k0 + 1) * 256 + b] = excl + v0;
    if (tid == 255) btot[(blockIdx.x >> 8) * 256 + b] = s[255];
}

__global__ __launch_bounds__(256) void k_bscan2(const int* __restrict__ btot,
                                                int* __restrict__ bstart_d,
                                                int* __restrict__ bstart_s) {
    __shared__ int s[256];
    int b = threadIdx.x;
    int v = btot[b];
    s[b] = v;
    __syncthreads();
    for (int off = 1; off < 256; off <<= 1) {
        int t = (b >= off) ? s[b - off] : 0;
        __syncthreads();
        s[b] += t;
        __syncthreads();
    }
    bstart_d[b] = s[b] - v;
    if (b == 0) bstart_d[256] = N_EDGES;
    __syncthreads();
    int v2 = btot[256 + b];
    s[b] = v2;
    __syncthreads();
    for (int off = 1; off < 256; off <<= 1) {
        int t = (b >= off) ? s[b - off] : 0;
        __syncthreads();
        s[b] += t;
        __syncthreads();
    }
    bstart_s[b] = s[b] - v2;
    if (b == 0) bstart_s[256] = N_EDGES;
}

// R15: LDS-staged scatter (verified win: WRITE-allocate traffic gone, dropped
// out of top-5). Locally sort chunk in LDS, copy out bucket-runs coalesced.
// dsw: {src | dst_local<<16 | bucket<<24, f32 w}; ssw: src(16b) | f16w<<16.
__global__ __launch_bounds__(256) void k_bscatter(const int* __restrict__ src,
                                                  const int* __restrict__ dst,
                                                  const float* __restrict__ w,
                                                  const int* __restrict__ bcnt_d,
                                                  const int* __restrict__ bcnt_s,
                                                  const int* __restrict__ bstart_d,
                                                  const int* __restrict__ bstart_s,
                                                  uint2* __restrict__ dsw,
                                                  unsigned* __restrict__ ssw) {
    __shared__ uint2 sbufd[CHUNK];       // 32 KB bucket-sorted dsw records
    __shared__ unsigned sbufs[CHUNK];    // 16 KB bucket-sorted ssw records
    __shared__ int lcd[256];
    __shared__ int lcs[256];
    __shared__ int curd_l[256];
    __shared__ int curs_l[256];
    __shared__ int gbase_d[256];
    __shared__ int gbase_s[256];
    int tid = threadIdx.x;
    lcd[tid] = 0; lcs[tid] = 0;
    __syncthreads();
    int base = blockIdx.x * CHUNK;
    // pass A: local counts
    for (int i = tid; i < CHUNK; i += 256) {
        atomicAdd(&lcd[dst[base + i] >> 8], 1);
        atomicAdd(&lcs[src[base + i] >> 8], 1);
    }
    __syncthreads();
    // in-place inclusive scans -> local exclusive offsets
    int vd = lcd[tid], vs = lcs[tid];
    for (int off = 1; off < 256; off <<= 1) {
        int td = (tid >= off) ? lcd[tid - off] : 0;
        int ts = (tid >= off) ? lcs[tid - off] : 0;
        __syncthreads();
        lcd[tid] += td; lcs[tid] += ts;
        __syncthreads();
    }
    int exd = lcd[tid] - vd, exs = lcs[tid] - vs;
    curd_l[tid] = exd;
    curs_l[tid] = exs;
    gbase_d[tid] = bcnt_d[blockIdx.x * 256 + tid] + bstart_d[tid] - exd;
    gbase_s[tid] = bcnt_s[blockIdx.x * 256 + tid] + bstart_s[tid] - exs;
    __syncthreads();
    // pass B: place into LDS at locally-sorted positions (chunk re-read L1-hot)
    for (int i = tid; i < CHUNK; i += 256) {
        int d = dst[base + i];
        int ss = src[base + i];
        float wi = w[base + i];
        int p = atomicAdd(&curd_l[d >> 8], 1);   // LDS atomic
        uint2 r;
        r.x = (unsigned)ss | ((unsigned)(d & 255) << 16) | ((unsigned)(d >> 8) << 24);
        r.y = __float_as_uint(wi);
        sbufd[p] = r;
        int q = atomicAdd(&curs_l[ss >> 8], 1);  // LDS atomic
        HBits hw; hw.h = __float2half(wi);
        sbufs[q] = (unsigned)ss | ((unsigned)hw.u << 16);
    }
    __syncthreads();
    // pass C: coalesced copy-out (consecutive i -> consecutive addr per run)
    for (int i = tid; i < CHUNK; i += 256) {
        uint2 r = sbufd[i];
        dsw[gbase_d[(r.x >> 24) & 255] + i] = r;
    }
    for (int i = tid; i < CHUNK; i += 256) {
        unsigned rs = sbufs[i];
        ssw[gbase_s[(rs >> 8) & 255] + i] = rs;
    }
}

// deg per src-bucket -> dinv (f16 w partials: ~0.05% deg error, negligible)
__global__ __launch_bounds__(256) void k_sdeg(const unsigned* __restrict__ ssw,
                                              const int* __restrict__ bstart_s,
                                              float* __restrict__ dinv) {
    __shared__ float h[256];
    int tid = threadIdx.x;
    int b = blockIdx.x;
    h[tid] = 0.f;
    __syncthreads();
    int e0 = bstart_s[b], e1 = bstart_s[b + 1];
    for (int i = e0 + tid; i < e1; i += 256) {
        unsigned r = ssw[i];
        HBits hb; hb.u = (unsigned short)(r >> 16);
        atomicAdd(&h[r & 255], __half2float(hb.h));  // LDS atomic
    }
    __syncthreads();
    int node = (b << 8) + tid;
    if (node < N_NODES) {
        float d = h[tid];
        dinv[node] = d > 0.f ? rsqrtf(fmaxf(d, 1e-30f)) : 0.f;
    }
}

// per-bucket CSR build + inline norm. Rows PADDED to multiples of 8 with
// zero entries (src=0, norm=0) so every row start is 8-aligned and spmm needs
// no guarded tail. csr entry = src(16b) | f16norm<<16. ri[node]={start,pcnt}.
__global__ __launch_bounds__(256) void k_bcsr(const uint2* __restrict__ dsw,
                                              const int* __restrict__ bstart_d,
                                              const float* __restrict__ dinv,
                                              uint2* __restrict__ ri,
                                              unsigned* __restrict__ csr4) {
    __shared__ int ncnt[256];
    __shared__ int cur[256];
    __shared__ int sc[256];
    __shared__ float ldinv[256];
    int tid = threadIdx.x;
    int b = blockIdx.x;
    int node = (b << 8) + tid;
    ncnt[tid] = 0;
    ldinv[tid] = (node < N_NODES) ? dinv[node] : 0.f;
    __syncthreads();
    int e0 = bstart_d[b], e1 = bstart_d[b + 1];
    for (int i = e0 + tid; i < e1; i += 256)
        atomicAdd(&ncnt[(dsw[i].x >> 16) & 255], 1);  // LDS atomic
    __syncthreads();
    int v = ncnt[tid];
    int pc = (v + 7) & ~7;                            // padded count
    sc[tid] = pc;
    __syncthreads();
    for (int off = 1; off < 256; off <<= 1) {
        int t = (tid >= off) ? sc[tid - off] : 0;
        __syncthreads();
        sc[tid] += t;
        __syncthreads();
    }
    int excl = sc[tid] - pc;
    cur[tid] = excl;
    int pbase = ((e0 + 7) & ~7) + 2048 * b;
    if (node < N_NODES) {
        uint2 r; r.x = (unsigned)(pbase + excl); r.y = (unsigned)pc;
        ri[node] = r;
    }
    __syncthreads();
    for (int i = e0 + tid; i < e1; i += 256) {
        uint2 sw = dsw[i];
        int srcn = sw.x & 0xFFFF;
        int ld = (sw.x >> 16) & 255;
        int p = pbase + atomicAdd(&cur[ld], 1);  // LDS atomic
        float nv = -dinv[srcn] * __uint_as_float(sw.y) * ldinv[ld];
        HBits hb; hb.h = __float2half(nv);
        csr4[p] = (unsigned)srcn | ((unsigned)hb.u << 16);
    }
    __syncthreads();
    // zero-norm fillers
    int st = pbase + excl;
    for (int i = v; i < pc; i++) csr4[st + i] = 0u;
}

// merged prep: x fp32 -> X f16 (blocks 0..6249), Wt builds (rest).
// Wt[n*128 + k], n in [0,3C): slice0 = 2*W2, slice1 = W1, slice2 = W0 - W2.
__device__ inline void wt_one(const float* __restrict__ W, __half* __restrict__ Wt,
                              int C, int i) {
    int n = i >> 7, k = i & 127;
    int slice = n / C, c = n % C;
    float v;
    if (slice == 0)      v = 2.f * W[(size_t)(256 + k) * C + c];
    else if (slice == 1) v = W[(size_t)(128 + k) * C + c];
    else                 v = W[(size_t)k * C + c] - W[(size_t)(256 + k) * C + c];
    Wt[i] = __float2half(v);
}

__global__ __launch_bounds__(256) void k_prep(const float* __restrict__ x,
                                              __half* __restrict__ X,
                                              const float* __restrict__ W0,
                                              const float* __restrict__ W1,
                                              const float* __restrict__ W2,
                                              __half* __restrict__ Wt0,
                                              __half* __restrict__ Wt1,
                                              __half* __restrict__ Wt2) {
    int bid = blockIdx.x, tid = threadIdx.x;
    if (bid < 6250) {
        int i = bid * 256 + tid;          // float4 index, 1.6M total
        float4 v = *(const float4*)&x[(size_t)i * 4];
        f16x4 o;
        o[0] = (_Float16)v.x; o[1] = (_Float16)v.y;
        o[2] = (_Float16)v.z; o[3] = (_Float16)v.w;
        *(f16x4*)&X[(size_t)i * 4] = o;
    } else if (bid < 6250 + 192) {
        wt_one(W0, Wt0, 128, (bid - 6250) * 256 + tid);
    } else if (bid < 6250 + 384) {
        wt_one(W1, Wt1, 128, (bid - 6250 - 192) * 256 + tid);
    } else {
        wt_one(W2, Wt2, 64, (bid - 6250 - 384) * 256 + tid);
    }
}

// ---------- SpMM: one wave per node, wide aligned csr loads ------
// R13/R14: fp8 gathers (P8/TMP8), 1 cache line per edge, WS 6.4 MB.
// R16: REVERTED the FPL=16 experiment (R15 spmm, +46% regression — VMEM
// instr count is NOT the bound; 8B/lane x 16 lanes/edge is the HW happy
// path). Kernel is per-node latency-chain bound; R16 hoists the Add load
// above the gather loop to overlap its latency with the gathers.
__device__ inline void mac_pair(const __half* __restrict__ Tbase, unsigned ea,
                                unsigned eb, int stin, float acc[8]) {
    f16x8 r0 = *(const f16x8*)&Tbase[(size_t)(ea & 0xFFFFu) * stin];
    f16x8 r1 = *(const f16x8*)&Tbase[(size_t)(eb & 0xFFFFu) * stin];
    unsigned np = (ea >> 16) | (eb & 0xFFFF0000u);
    f16x2 nv; __builtin_memcpy(&nv, &np, 4);
    #pragma unroll
    for (int f = 0; f < 8; f++) {
        f16x2 h; h[0] = r0[f]; h[1] = r1[f];
        acc[f] = __builtin_amdgcn_fdot2(h, nv, acc[f], false);
    }
}

// convert 8 fp8 (uint2) + f16 norm (hi bits of ce) -> acc += n * v
__device__ inline void macv_f8(uint2 v, unsigned ce, float acc[8]) {
    HBits hb; hb.u = (unsigned short)(ce >> 16);
    float n = __half2float(hb.h);
    f32x2 p0 = __builtin_amdgcn_cvt_pk_f32_fp8(v.x, false);
    f32x2 p1 = __builtin_amdgcn_cvt_pk_f32_fp8(v.x, true);
    f32x2 p2 = __builtin_amdgcn_cvt_pk_f32_fp8(v.y, false);
    f32x2 p3 = __builtin_amdgcn_cvt_pk_f32_fp8(v.y, true);
    acc[0] = fmaf(n, p0[0], acc[0]);
    acc[1] = fmaf(n, p0[1], acc[1]);
    acc[2] = fmaf(n, p1[0], acc[2]);
    acc[3] = fmaf(n, p1[1], acc[3]);
    acc[4] = fmaf(n, p2[0], acc[4]);
    acc[5] = fmaf(n, p2[1], acc[5]);
    acc[6] = fmaf(n, p3[0], acc[6]);
    acc[7] = fmaf(n, p3[1], acc[7]);
}

__device__ inline void mac_e8(const unsigned char* __restrict__ Tb, unsigned ce,
                              int stin, float acc[8]) {
    uint2 v = *(const uint2*)&Tb[(size_t)(ce & 0xFFFFu) * (size_t)stin];
    macv_f8(v, ce, acc);
}

template <int ST_IN, int ST_ADD, int ST_OUT, int FW, int SIG, int F32, int GF8,
          int F8OUT>
__global__ __launch_bounds__(256) void k_spmm(const void* __restrict__ Xin,
                                              const __half* __restrict__ Add,
                                              void* __restrict__ outp,
                                              const float* __restrict__ bias,
                                              const uint2* __restrict__ ri,
                                              const unsigned* __restrict__ csr4) {
    constexpr int NL = FW / 8;      // feature lanes per edge (16 or 8)
    constexpr int EG = 64 / NL;     // edge groups (4 or 8)
    int node = blockIdx.x * 4 + (threadIdx.x >> 6);
    int lane = threadIdx.x & 63;
    int eg = lane / NL;
    int fs = lane % NL;
    uint2 rv = ri[node];
    int s = (int)rv.x;
    int e = s + (int)rv.y;                  // count is multiple of 8
    const __half* Tbase = (const __half*)Xin + fs * 8;
    const unsigned char* Tb8 = (const unsigned char*)Xin + fs * 8;
    // R16: hoist Add load -- independent of the reduction, overlaps gathers
    f16x8 av = *(const f16x8*)&Add[(size_t)node * ST_ADD + fs * 8];
    float acc[8];
    #pragma unroll
    for (int f = 0; f < 8; f++) acc[f] = 0.f;

    int j = s;
    if (GF8) {
        if (EG == 4) {                      // FW=128: group owns 8 edges/iter
            for (; j + 32 <= e; j += 32) {
                uint4 c0 = *(const uint4*)&csr4[j + 4 * eg];
                uint4 c1 = *(const uint4*)&csr4[j + 16 + 4 * eg];
                unsigned ce[8] = {c0.x, c0.y, c0.z, c0.w, c1.x, c1.y, c1.z, c1.w};
                uint2 g[8];
                #pragma unroll
                for (int k = 0; k < 8; k++)
                    g[k] = *(const uint2*)&Tb8[(size_t)(ce[k] & 0xFFFFu) * (size_t)ST_IN];
                #pragma unroll
                for (int k = 0; k < 8; k++) macv_f8(g[k], ce[k], acc);
            }
            if (j + 16 <= e) {
                uint4 c0 = *(const uint4*)&csr4[j + 4 * eg];
                unsigned ce[4] = {c0.x, c0.y, c0.z, c0.w};
                uint2 g[4];
                #pragma unroll
                for (int k = 0; k < 4; k++)
                    g[k] = *(const uint2*)&Tb8[(size_t)(ce[k] & 0xFFFFu) * (size_t)ST_IN];
                #pragma unroll
                for (int k = 0; k < 4; k++) macv_f8(g[k], ce[k], acc);
                j += 16;
            }
            if (j + 8 <= e) {
                uint2 c = *(const uint2*)&csr4[j + 2 * eg];
                mac_e8(Tb8, c.x, ST_IN, acc);
                mac_e8(Tb8, c.y, ST_IN, acc);
            }
        } else {                            // FW=64, EG=8: group owns 4/iter
            for (; j + 32 <= e; j += 32) {
                uint4 c0 = *(const uint4*)&csr4[j + 4 * eg];
                unsigned ce[4] = {c0.x, c0.y, c0.z, c0.w};
                uint2 g[4];
                #pragma unroll
                for (int k = 0; k < 4; k++)
                    g[k] = *(const uint2*)&Tb8[(size_t)(ce[k] & 0xFFFFu) * (size_t)ST_IN];
                #pragma unroll
                for (int k = 0; k < 4; k++) macv_f8(g[k], ce[k], acc);
            }
            if (j + 16 <= e) {
                uint2 c = *(const uint2*)&csr4[j + 2 * eg];
                mac_e8(Tb8, c.x, ST_IN, acc);
                mac_e8(Tb8, c.y, ST_IN, acc);
                j += 16;
            }
            if (j + 8 <= e) {
                uint2 c = *(const uint2*)&csr4[j + 2 * (eg & 3)];
                unsigned ea = c.x, eb = c.y;
                if (eg >= 4) { ea &= 0xFFFFu; eb &= 0xFFFFu; }  // zero norms
                mac_e8(Tb8, ea, ST_IN, acc);
                mac_e8(Tb8, eb, ST_IN, acc);
            }
        }
    } else if (EG == 4) {                   // f16, FW=128
        for (; j + 32 <= e; j += 32) {
            uint4 c0 = *(const uint4*)&csr4[j + 4 * eg];
            uint4 c1 = *(const uint4*)&csr4[j + 16 + 4 * eg];
            unsigned ea[4] = {c0.x, c0.z, c1.x, c1.z};
            unsigned eb[4] = {c0.y, c0.w, c1.y, c1.w};
            f16x8 r0[4], r1[4];
            #pragma unroll
            for (int k = 0; k < 4; k++) {
                r0[k] = *(const f16x8*)&Tbase[(size_t)(ea[k] & 0xFFFFu) * ST_IN];
                r1[k] = *(const f16x8*)&Tbase[(size_t)(eb[k] & 0xFFFFu) * ST_IN];
            }
            #pragma unroll
            for (int k = 0; k < 4; k++) {
                unsigned np = (ea[k] >> 16) | (eb[k] & 0xFFFF0000u);
                f16x2 nv; __builtin_memcpy(&nv, &np, 4);
                #pragma unroll
                for (int f = 0; f < 8; f++) {
                    f16x2 h; h[0] = r0[k][f]; h[1] = r1[k][f];
                    acc[f] = __builtin_amdgcn_fdot2(h, nv, acc[f], false);
                }
            }
        }
        if (j + 16 <= e) {
            uint4 c0 = *(const uint4*)&csr4[j + 4 * eg];
            mac_pair(Tbase, c0.x, c0.y, ST_IN, acc);
            mac_pair(Tbase, c0.z, c0.w, ST_IN, acc);
            j += 16;
        }
        if (j + 8 <= e) {
            uint2 c = *(const uint2*)&csr4[j + 2 * eg];
            mac_pair(Tbase, c.x, c.y, ST_IN, acc);
        }
    } else {                                // f16, FW=64, EG=8
        for (; j + 32 <= e; j += 32) {
            uint4 c0 = *(const uint4*)&csr4[j + 4 * eg];
            unsigned ea[2] = {c0.x, c0.z};
            unsigned eb[2] = {c0.y, c0.w};
            f16x8 r0[2], r1[2];
            #pragma unroll
            for (int k = 0; k < 2; k++) {
                r0[k] = *(const f16x8*)&Tbase[(size_t)(ea[k] & 0xFFFFu) * ST_IN];
                r1[k] = *(const f16x8*)&Tbase[(size_t)(eb[k] & 0xFFFFu) * ST_IN];
            }
            #pragma unroll
            for (int k = 0; k < 2; k++) {
                unsigned np = (ea[k] >> 16) | (eb[k] & 0xFFFF0000u);
                f16x2 nv; __builtin_memcpy(&nv, &np, 4);
                #pragma unroll
                for (int f = 0; f < 8; f++) {
                    f16x2 h; h[0] = r0[k][f]; h[1] = r1[k][f];
                    acc[f] = __builtin_amdgcn_fdot2(h, nv, acc[f], false);
                }
            }
        }
        if (j + 16 <= e) {
            uint2 c = *(const uint2*)&csr4[j + 2 * eg];
            mac_pair(Tbase, c.x, c.y, ST_IN, acc);
            j += 16;
        }
        if (j + 8 <= e) {
            uint2 c = *(const uint2*)&csr4[j + 2 * (eg & 3)];
            unsigned ea = c.x, eb = c.y;
            if (eg >= 4) { ea &= 0xFFFFu; eb &= 0xFFFFu; }  // zero norms (dup groups)
            mac_pair(Tbase, ea, eb, ST_IN, acc);
        }
    }
    // reduce edge-group partials
    #pragma unroll
    for (int f = 0; f < 8; f++)
        for (int m = NL; m < 64; m <<= 1)
            acc[f] += __shfl_xor(acc[f], m);
    if (eg == 0) {
        float v[8];
        #pragma unroll
        for (int f = 0; f < 8; f++) v[f] = acc[f] + (float)av[f];
        if (SIG) {
            #pragma unroll
            for (int f = 0; f < 8; f++) {
                v[f] += bias[fs * 8 + f];
                v[f] = 1.f / (1.f + expf(-v[f]));
            }
        }
        if (F32) {
            float* o = (float*)outp + (size_t)node * ST_OUT + fs * 8;
            float4 o0; o0.x = v[0]; o0.y = v[1]; o0.z = v[2]; o0.w = v[3];
            float4 o1; o1.x = v[4]; o1.y = v[5]; o1.z = v[6]; o1.w = v[7];
            *(float4*)&o[0] = o0;
            *(float4*)&o[4] = o1;
        } else if (F8OUT) {
            int w0 = __builtin_amdgcn_cvt_pk_fp8_f32(v[0], v[1], 0, false);
            w0 = __builtin_amdgcn_cvt_pk_fp8_f32(v[2], v[3], w0, true);
            int w1 = __builtin_amdgcn_cvt_pk_fp8_f32(v[4], v[5], 0, false);
            w1 = __builtin_amdgcn_cvt_pk_fp8_f32(v[6], v[7], w1, true);
            uint2 o; o.x = (unsigned)w0; o.y = (unsigned)w1;
            *(uint2*)((unsigned char*)outp + (size_t)node * ST_OUT + fs * 8) = o;
        } else {
            f16x8 o;
            #pragma unroll
            for (int f = 0; f < 8; f++) o[f] = (_Float16)v[f];
            *(f16x8*)((__half*)outp + (size_t)node * ST_OUT + fs * 8) = o;
        }
    }
}

// ---------- MFMA GEMM: [P8|G] = X[M x 128] @ Wt^T ---------------------------
// P slice (first CC cols, = 2*W2 weights) written as fp8 e4m3 to packed P8
// [M x CC]; Q,S slices written f16 to G stride STG=2*CC (Q@0, S@CC).
template <int CC, int STG>
__global__ __launch_bounds__(256) void k_gemm(const __half* __restrict__ A,
                                              const __half* __restrict__ Wt,
                                              __half* __restrict__ G,
                                              unsigned char* __restrict__ P8,
                                              int M) {
    constexpr int N3 = 3 * CC;
    constexpr int NF = N3 / 16;
    constexpr int NP = CC / 16;       // fp8 P fragments
    __shared__ _Float16 As[64][40];
    __shared__ _Float16 Bs[N3][40];
    int tid = threadIdx.x;
    int wave = tid >> 6, lane = tid & 63;
    int lm = lane & 15, lq = lane >> 4;
    int m0 = blockIdx.x * 64;
    f32x4 acc[NF];
    for (int nf = 0; nf < NF; nf++) acc[nf] = (f32x4)0.0f;

    for (int k0 = 0; k0 < 128; k0 += 32) {
        {
            int r = tid >> 2, q = tid & 3;
            int row = m0 + r;
            if (row >= M) row = M - 1;
            *(f16x8*)&As[r][q * 8] = *(const f16x8*)&A[(size_t)row * 128 + k0 + q * 8];
        }
        for (int i = 0; i < N3 / 64; i++) {
            int idx = tid + i * 256;
            int n = idx >> 2, q = idx & 3;
            *(f16x8*)&Bs[n][q * 8] = *(const f16x8*)&Wt[(size_t)n * 128 + k0 + q * 8];
        }
        __syncthreads();
        f16x8 a = *(const f16x8*)&As[wave * 16 + lm][lq * 8];
        for (int nf = 0; nf < NF; nf++) {
            f16x8 b = *(const f16x8*)&Bs[nf * 16 + lm][lq * 8];
            acc[nf] = __builtin_amdgcn_mfma_f32_16x16x32_f16(a, b, acc[nf], 0, 0, 0);
        }
        __syncthreads();
    }
    for (int nf = 0; nf < NF; nf++) {
        for (int r = 0; r < 4; r++) {
            int grow = m0 + wave * 16 + lq * 4 + r;
            int col = nf * 16 + lm;
            if (grow < M) {
                if (nf < NP) {
                    int pk = __builtin_amdgcn_cvt_pk_fp8_f32(acc[nf][r], acc[nf][r],
                                                             0, false);
                    P8[(size_t)grow * CC + col] = (unsigned char)(pk & 0xFF);
                } else {
                    G[(size_t)grow * STG + (col - CC)] = __float2half(acc[nf][r]);
                }
            }
        }
    }
}

extern "C" void kernel_launch(void* const* d_in, const int* in_sizes, int n_in,
                              void* d_out, int out_size, void* d_ws, size_t ws_size,
                              hipStream_t stream) {
    const float* x  = (const float*)d_in[0];
    const int*   ei = (const int*)d_in[1];
    const float* ew = (const float*)d_in[2];
    const float* W0 = (const float*)d_in[3];
    const float* b0 = (const float*)d_in[4];
    const float* W1 = (const float*)d_in[5];
    const float* b1 = (const float*)d_in[6];
    const float* W2 = (const float*)d_in[7];
    const float* b2 = (const float*)d_in[8];
    const int* src = ei;
    const int* dst = ei + N_EDGES;

    char* ws = (char*)d_ws;
    size_t off = 0;
    auto alloc = [&](size_t bytes) -> char* {
        size_t p = (off + 255) & ~(size_t)255;
        off = p + bytes;
        return ws + p;
    };
    __half*   X      = (__half*)alloc((size_t)N_NODES * 128 * 2);
    __half*   G      = (__half*)alloc((size_t)N_NODES * 256 * 2);   // [Q|S], stride 256
    __half*   TMP    = (__half*)alloc((size_t)N_NODES * 128 * 2);   // L*P + Q (layer 2, f16)
    unsigned char* P8 = (unsigned char*)alloc((size_t)N_NODES * 128); // fp8 P, packed
    unsigned char* TMP8 = (unsigned char*)alloc((size_t)N_NODES * 128); // fp8 TMP (L0/L1)
    unsigned* csr4   = (unsigned*)alloc((size_t)CSR_CAP * 4);       // padded CSR
    uint2*    ri     = (uint2*)alloc((size_t)N_NODES * 8);          // (start, pcount)
    uint2*    dsw    = (uint2*)alloc((size_t)N_EDGES * 8);
    unsigned* ssw    = (unsigned*)alloc((size_t)N_EDGES * 4);       // src | f16w<<16
    int*      bcnt_d = (int*)alloc((size_t)EBLK * 256 * 4);
    int*      bcnt_s = (int*)alloc((size_t)EBLK * 256 * 4);
    int*      btot   = (int*)alloc(512 * 4);
    int*      bstart_d = (int*)alloc(257 * 4);
    int*      bstart_s = (int*)alloc(257 * 4);
    float*    dinv   = (float*)alloc((size_t)N_NODES * 4);
    __half*   Wt0    = (__half*)alloc((size_t)384 * 128 * 2);
    __half*   Wt1    = (__half*)alloc((size_t)384 * 128 * 2);
    __half*   Wt2    = (__half*)alloc((size_t)192 * 128 * 2);

    // dual bucket sort; zero device-scope atomics anywhere
    k_bcount<<<EBLK, 256, 0, stream>>>(src, dst, bcnt_d, bcnt_s);
    k_bscan1<<<512, 256, 0, stream>>>(bcnt_d, bcnt_s, btot);
    k_bscan2<<<1, 256, 0, stream>>>(btot, bstart_d, bstart_s);
    k_bscatter<<<EBLK, 256, 0, stream>>>(src, dst, ew, bcnt_d, bcnt_s,
                                         bstart_d, bstart_s, dsw, ssw);
    k_sdeg<<<NBUCK, 256, 0, stream>>>(ssw, bstart_s, dinv);
    k_bcsr<<<NBUCK, 256, 0, stream>>>(dsw, bstart_d, dinv, ri, csr4);

    k_prep<<<6250 + 192 + 192 + 96, 256, 0, stream>>>(x, X, W0, W1, W2, Wt0, Wt1, Wt2);

    int gb = (N_NODES + 63) / 64;   // 782
    int sb = N_NODES / 4;           // 12500
    // layer 0: P8 = fp8(X @ 2W2), G = f16(X @ [W1 | W0-W2])  (Q@0, S@128)
    // TMP8 = fp8(L*P + Q);  X = sigmoid(L*TMP8 + S + b0)
    k_gemm<128, 256><<<gb, 256, 0, stream>>>(X, Wt0, G, P8, N_NODES);
    k_spmm<128, 256, 128, 128, 0, 0, 1, 1><<<sb, 256, 0, stream>>>(P8, G, TMP8,
                                                                   nullptr, ri, csr4);
    k_spmm<128, 256, 128, 128, 1, 0, 1, 0><<<sb, 256, 0, stream>>>(TMP8, G + 128, X,
                                                                   b0, ri, csr4);
    // layer 1
    k_gemm<128, 256><<<gb, 256, 0, stream>>>(X, Wt1, G, P8, N_NODES);
    k_spmm<128, 256, 128, 128, 0, 0, 1, 1><<<sb, 256, 0, stream>>>(P8, G, TMP8,
                                                                   nullptr, ri, csr4);
    k_spmm<128, 256, 128, 128, 1, 0, 1, 0><<<sb, 256, 0, stream>>>(TMP8, G + 128, X,
                                                                   b1, ri, csr4);
    // layer 2 (C=64): G stride 128 (Q@0, S@64); TMP stays f16 (feeds output)
    k_gemm<64, 128><<<gb, 256, 0, stream>>>(X, Wt2, G, P8, N_NODES);
    k_spmm<64, 128, 64, 64, 0, 0, 1, 0><<<sb, 256, 0, stream>>>(P8, G, TMP,
                                                                nullptr, ri, csr4);
    k_spmm<64, 128, 64, 64, 1, 1, 0, 0><<<sb, 256, 0, stream>>>(TMP, G + 64, d_out,
                                                                b2, ri, csr4);
}